// Round 2
// baseline (854.299 us; speedup 1.0000x reference)
//
#include <hip/hip_runtime.h>
#include <cstdint>
#include <cstddef>

// LatentNeuralSDE: 100 sequential EM steps, B=32768, LAT=10.
// Persistent kernel, 512 blocks x 256 thr; wave owns 16 batch rows; no
// in-loop barriers (all LDS traffic is wave-private; per-wave DS ops are
// in-order). R2: permuted activation storage (col = n*8+t) so each lane
// packs its 8 outputs into one ds_write_b128; W2 frags half in VGPRs /
// half in frag-linear LDS (conflict-free self-slot reads); v_perm bf16
// pair-packing; bias folds; pointer-increment global addressing.

#define B_TOT 32768
#define NSTEP 100
#define MT    64

typedef __attribute__((ext_vector_type(8))) short sh8;
typedef __attribute__((ext_vector_type(4))) float f32x4;
typedef __attribute__((ext_vector_type(4))) unsigned int u32x4;

struct __align__(16) LdsSteady {
  short h[MT][136];    // hidden slab, storage col c -> feature (c&7)*16+(c>>3)
  short hg[MT][40];    // diffusion hidden, col c -> feature (c&1)*16+(c>>1)
  short zb[MT][40];    // [z0..z9, t, zeros...]; 80B rows (16B aligned)
};
struct __align__(16) LdsInit { float ar[MT][100]; };   // [a(64), r(32)]
struct __align__(16) Lds {
  union { LdsSteady s; LdsInit i; } u;   // 27648 B
  short w2l[16][64][8];                  // W2 frags t2=4..7, [idx][lane][8]
  float tsl[104];
};

static __device__ __forceinline__ short f2bf(float v) {  // RTNE (one-time paths)
  unsigned u = __builtin_bit_cast(unsigned, v);
  u += 0x7fffu + ((u >> 16) & 1u);
  return (short)(u >> 16);
}
static __device__ __forceinline__ short f2bf_ru(float v) {  // cheap round
  unsigned u = __builtin_bit_cast(unsigned, v) + 0x8000u;
  return (short)(u >> 16);
}
// pack two floats -> (bf16(hi)<<16)|bf16(lo) : 2 adds + 1 v_perm
static __device__ __forceinline__ unsigned pk2(float lo, float hi) {
  unsigned a = __builtin_bit_cast(unsigned, lo) + 0x8000u;
  unsigned b = __builtin_bit_cast(unsigned, hi) + 0x8000u;
  return __builtin_amdgcn_perm(b, a, 0x07060302u);
}
static __device__ __forceinline__ float tanh_fast(float x) {
  float e = exp2f(x * 2.8853900817779268f);
  float r = __builtin_amdgcn_rcpf(e + 1.0f);
  return __builtin_fmaf(-2.0f, r, 1.0f);
}
static __device__ __forceinline__ float tanh_b(float x, float kb) {  // tanh(x+b)
  float e = exp2f(__builtin_fmaf(x, 2.8853900817779268f, kb));
  float r = __builtin_amdgcn_rcpf(e + 1.0f);
  return __builtin_fmaf(-2.0f, r, 1.0f);
}
static __device__ __forceinline__ float softplus_fast(float x) {
  float e = exp2f(x * 1.4426950408889634f);
  float l = log2f(e + 1.0f) * 0.6931471805599453f;
  return (x > 20.0f) ? x : l;
}

__global__ __launch_bounds__(256, 2)
void sde_kernel(const float* __restrict__ z0, const float* __restrict__ activity,
                const float* __restrict__ rest, const float* __restrict__ ts,
                const float* __restrict__ noise,
                const float* __restrict__ aW1, const float* __restrict__ ab1,
                const float* __restrict__ aW2, const float* __restrict__ ab2,
                const float* __restrict__ rW1, const float* __restrict__ rb1,
                const float* __restrict__ rW2, const float* __restrict__ rb2,
                const float* __restrict__ dW1, const float* __restrict__ db1,
                const float* __restrict__ dW2, const float* __restrict__ db2,
                const float* __restrict__ dW3, const float* __restrict__ db3,
                const float* __restrict__ gW1, const float* __restrict__ gb1,
                const float* __restrict__ gW2, const float* __restrict__ gb2,
                float* __restrict__ out)
{
  __shared__ Lds lds;
  const int tid  = threadIdx.x;
  const int lane = tid & 63;
  const int wave = tid >> 6;
  const int n    = lane & 15;
  const int quad = lane >> 4;
  const int slab = wave * 16;
  const int row0 = slab + quad * 4;
  const int mblk = blockIdx.x * MT;

  // ---------------- prologue: ts table ----------------
  if (tid < 101) lds.tsl[tid] = ts[tid];
  float tcur = ts[0];

  // ---------------- fragment builds (registers + w2l) ----------------
  // L1 B-frags: true feature col t*16+n, k-rows 0..9 = z, 10 = t, rest 0
  sh8 z1f[8];
  #pragma unroll
  for (int t = 0; t < 8; ++t) {
    short tmp[8];
    #pragma unroll
    for (int j = 0; j < 8; ++j) {
      int k = quad * 8 + j;
      float v = 0.0f;
      if (k < 10) v = dW1[k * 128 + t * 16 + n];
      else if (k == 10) v = dW1[106 * 128 + t * 16 + n];
      tmp[j] = f2bf(v);
    }
    z1f[t] = (sh8){tmp[0],tmp[1],tmp[2],tmp[3],tmp[4],tmp[5],tmp[6],tmp[7]};
  }
  // W2 frags against permuted storage: element j = W2[j*16+kt*4+quad][t2*16+n]
  sh8 w2r[4][4];
  #pragma unroll
  for (int t2 = 0; t2 < 8; ++t2) {
    #pragma unroll
    for (int kt = 0; kt < 4; ++kt) {
      short tmp[8];
      #pragma unroll
      for (int j = 0; j < 8; ++j)
        tmp[j] = f2bf(dW2[(j * 16 + kt * 4 + quad) * 128 + t2 * 16 + n]);
      sh8 f = (sh8){tmp[0],tmp[1],tmp[2],tmp[3],tmp[4],tmp[5],tmp[6],tmp[7]};
      if (t2 < 4) w2r[t2][kt] = f;
      else *(sh8*)&lds.w2l[(t2 - 4) * 4 + kt][lane][0] = f;
    }
  }
  // W3 frags (same row permutation)
  sh8 w3f[4];
  #pragma unroll
  for (int kt = 0; kt < 4; ++kt) {
    short tmp[8];
    #pragma unroll
    for (int j = 0; j < 8; ++j) {
      int rr = j * 16 + kt * 4 + quad;
      tmp[j] = f2bf((n < 10) ? dW3[rr * 10 + n] : 0.0f);
    }
    w3f[kt] = (sh8){tmp[0],tmp[1],tmp[2],tmp[3],tmp[4],tmp[5],tmp[6],tmp[7]};
  }
  // G1 frags (natural k = z-features)
  sh8 g1f[2];
  #pragma unroll
  for (int t = 0; t < 2; ++t) {
    short tmp[8];
    #pragma unroll
    for (int j = 0; j < 8; ++j) {
      int k = quad * 8 + j;
      float v = 0.0f;
      if (k < 10) v = gW1[k * 32 + t * 16 + n];
      else if (k == 10) v = gW1[10 * 32 + t * 16 + n];
      tmp[j] = f2bf(v);
    }
    g1f[t] = (sh8){tmp[0],tmp[1],tmp[2],tmp[3],tmp[4],tmp[5],tmp[6],tmp[7]};
  }
  // G2 frag against hg permutation: k -> feature (k&1)*16 + (k>>1)
  sh8 g2f;
  {
    short tmp[8];
    #pragma unroll
    for (int j = 0; j < 8; ++j) {
      int k = quad * 8 + j;
      int f = (k & 1) * 16 + (k >> 1);
      tmp[j] = f2bf((n < 10) ? gW2[f * 10 + n] : 0.0f);
    }
    g2f = (sh8){tmp[0],tmp[1],tmp[2],tmp[3],tmp[4],tmp[5],tmp[6],tmp[7]};
  }
  // bias folds
  float kb2[8];
  #pragma unroll
  for (int t = 0; t < 8; ++t) kb2[t] = db2[t * 16 + n] * 2.8853900817779268f;
  float gb1a = gb1[n], gb1b_ = gb1[16 + n];
  float db3r = (n < 10) ? db3[n] : 0.0f;
  float gb2r = (n < 10) ? gb2[n] : 0.0f;
  const f32x4 cg0 = {gb1a, gb1a, gb1a, gb1a};
  const f32x4 cg1 = {gb1b_, gb1b_, gb1b_, gb1b_};
  const f32x4 cd3 = {db3r, db3r, db3r, db3r};
  const f32x4 cg2 = {gb2r, gb2r, gb2r, gb2r};
  const f32x4 zc  = {0.0f, 0.0f, 0.0f, 0.0f};

  // ---------------- encoders -> ar ----------------
  {
    const int e = tid >> 2, p = tid & 3;
    const int eg = mblk + e;
    float act[6], rst[3];
    #pragma unroll
    for (int i = 0; i < 6; ++i) act[i] = activity[eg * 6 + i];
    #pragma unroll
    for (int i = 0; i < 3; ++i) rst[i] = rest[eg * 3 + i];
    float ha[32];
    for (int j = 0; j < 32; ++j) {
      float s = ab1[j];
      #pragma unroll
      for (int i = 0; i < 6; ++i) s = __builtin_fmaf(act[i], aW1[i * 32 + j], s);
      ha[j] = fmaxf(s, 0.0f);
    }
    float hr[16];
    for (int j = 0; j < 16; ++j) {
      float s = rb1[j];
      #pragma unroll
      for (int i = 0; i < 3; ++i) s = __builtin_fmaf(rst[i], rW1[i * 16 + j], s);
      hr[j] = fmaxf(s, 0.0f);
    }
    for (int oo = 0; oo < 24; ++oo) {
      int o = p * 24 + oo;
      float v;
      if (o < 64) {
        v = ab2[o];
        for (int j = 0; j < 32; ++j) v = __builtin_fmaf(ha[j], aW2[j * 64 + o], v);
      } else {
        int ro = o - 64;
        v = rb2[ro];
        for (int j = 0; j < 16; ++j) v = __builtin_fmaf(hr[j], rW2[j * 32 + ro], v);
      }
      lds.u.i.ar[e][o] = v;
    }
  }
  __syncthreads();

  // ---------------- c1 context fold (C operand for L1) ----------------
  f32x4 c1v[8];
  #pragma unroll
  for (int t = 0; t < 8; ++t) {
    float b = db1[t * 16 + n];
    c1v[t] = (f32x4){b, b, b, b};
  }
  for (int k = 0; k < 96; ++k) {
    float w[8];
    #pragma unroll
    for (int t = 0; t < 8; ++t) w[t] = dW1[(10 + k) * 128 + t * 16 + n];
    #pragma unroll
    for (int r = 0; r < 4; ++r) {
      float av = lds.u.i.ar[row0 + r][k];
      #pragma unroll
      for (int t = 0; t < 8; ++t) c1v[t][r] = __builtin_fmaf(av, w[t], c1v[t][r]);
    }
  }
  __syncthreads();   // ar dead; steady region live. Last barrier.

  // ---------------- zb init (wave-private), z0 load, out[0] ----------------
  {
    short* zp = &lds.u.s.zb[slab][0];
    for (int i = lane; i < 16 * 40; i += 64) zp[i] = 0;
  }
  float zreg[4];
  {
    float* op0 = out + (size_t)(mblk + row0) * 10 + n;
    #pragma unroll
    for (int r = 0; r < 4; ++r) {
      float v = (n < 10) ? z0[(size_t)(mblk + row0 + r) * 10 + n] : 0.0f;
      zreg[r] = v;
      if (n < 10) op0[r * 10] = v;
    }
    #pragma unroll
    for (int r = 0; r < 4; ++r) {
      if (n < 10)       lds.u.s.zb[row0 + r][n]  = f2bf_ru(zreg[r]);
      else if (n == 10) lds.u.s.zb[row0 + r][10] = f2bf_ru(tcur);
    }
  }

  // precomputed addresses
  const short* zb_rd = &lds.u.s.zb[slab + n][quad * 8];
  const short* h_rd  = &lds.u.s.h[slab + n][quad * 8];
  const short* hg_rd = &lds.u.s.hg[slab + n][quad * 8];
  const float* np = noise + (size_t)(mblk + row0) * 10 + n;
  float*       op = out + (size_t)B_TOT * 10 + (size_t)(mblk + row0) * 10 + n;

  #pragma unroll 1
  for (int s = 0; s < NSTEP; ++s) {
    float tnext = lds.tsl[s + 1];
    float dtv   = tnext - tcur;
    float sdt   = sqrtf(dtv);

    // noise prefetch (used ~whole step later)
    float eps[4] = {0.0f, 0.0f, 0.0f, 0.0f};
    if (n < 10) { eps[0] = np[0]; eps[1] = np[10]; eps[2] = np[20]; eps[3] = np[30]; }
    np += (size_t)B_TOT * 10;

    sh8 zA = *(const sh8*)zb_rd;

    // ---- diffusion hidden: hg = softplus(z,t @ G1 + gb1) ----
    {
      f32x4 g0 = __builtin_amdgcn_mfma_f32_16x16x32_bf16(zA, g1f[0], cg0, 0, 0, 0);
      f32x4 g1 = __builtin_amdgcn_mfma_f32_16x16x32_bf16(zA, g1f[1], cg1, 0, 0, 0);
      #pragma unroll
      for (int r = 0; r < 4; ++r)
        *(unsigned*)&lds.u.s.hg[row0 + r][n * 2] =
            pk2(softplus_fast(g0[r]), softplus_fast(g1[r]));
    }

    // ---- drift L1: h1 = tanh(z,t @ W1z + c1) ----
    {
      f32x4 a1[8];
      #pragma unroll
      for (int t = 0; t < 8; ++t)
        a1[t] = __builtin_amdgcn_mfma_f32_16x16x32_bf16(zA, z1f[t], c1v[t], 0, 0, 0);
      #pragma unroll
      for (int r = 0; r < 4; ++r) {
        u32x4 w;
        w.x = pk2(tanh_fast(a1[0][r]), tanh_fast(a1[1][r]));
        w.y = pk2(tanh_fast(a1[2][r]), tanh_fast(a1[3][r]));
        w.z = pk2(tanh_fast(a1[4][r]), tanh_fast(a1[5][r]));
        w.w = pk2(tanh_fast(a1[6][r]), tanh_fast(a1[7][r]));
        *(u32x4*)&lds.u.s.h[row0 + r][n * 8] = w;
      }
    }

    // ---- drift L2: h2 = tanh(h1 @ W2 + db2) ----
    {
      sh8 a2k[4];
      #pragma unroll
      for (int kt = 0; kt < 4; ++kt)
        a2k[kt] = *(const sh8*)(h_rd + kt * 32);
      f32x4 a2[8];
      #pragma unroll
      for (int t2 = 0; t2 < 8; ++t2) {
        f32x4 acc = zc;
        #pragma unroll
        for (int kt = 0; kt < 4; ++kt) {
          sh8 b = (t2 < 4) ? w2r[t2][kt]
                           : *(const sh8*)&lds.w2l[(t2 - 4) * 4 + kt][lane][0];
          acc = __builtin_amdgcn_mfma_f32_16x16x32_bf16(a2k[kt], b, acc, 0, 0, 0);
        }
        a2[t2] = acc;
      }
      #pragma unroll
      for (int r = 0; r < 4; ++r) {
        u32x4 w;
        w.x = pk2(tanh_b(a2[0][r], kb2[0]), tanh_b(a2[1][r], kb2[1]));
        w.y = pk2(tanh_b(a2[2][r], kb2[2]), tanh_b(a2[3][r], kb2[3]));
        w.z = pk2(tanh_b(a2[4][r], kb2[4]), tanh_b(a2[5][r], kb2[5]));
        w.w = pk2(tanh_b(a2[6][r], kb2[6]), tanh_b(a2[7][r], kb2[7]));
        *(u32x4*)&lds.u.s.h[row0 + r][n * 8] = w;
      }
    }

    // ---- drift L3 + diffusion out ----
    f32x4 accd = cd3;
    {
      sh8 a3k[4];
      #pragma unroll
      for (int kt = 0; kt < 4; ++kt)
        a3k[kt] = *(const sh8*)(h_rd + kt * 32);
      #pragma unroll
      for (int kt = 0; kt < 4; ++kt)
        accd = __builtin_amdgcn_mfma_f32_16x16x32_bf16(a3k[kt], w3f[kt], accd, 0, 0, 0);
    }
    f32x4 accf;
    {
      sh8 ag = *(const sh8*)hg_rd;
      accf = __builtin_amdgcn_mfma_f32_16x16x32_bf16(ag, g2f, cg2, 0, 0, 0);
    }

    // ---- EM update, out store, zb refresh ----
    #pragma unroll
    for (int r = 0; r < 4; ++r) {
      float d = __builtin_fmaf(accd[r], dtv, zreg[r]);
      zreg[r] = __builtin_fmaf(accf[r] * sdt, eps[r], d);
    }
    if (n < 10) {
      op[0] = zreg[0]; op[10] = zreg[1]; op[20] = zreg[2]; op[30] = zreg[3];
    }
    op += (size_t)B_TOT * 10;
    #pragma unroll
    for (int r = 0; r < 4; ++r) {
      if (n < 10)       lds.u.s.zb[row0 + r][n]  = f2bf_ru(zreg[r]);
      else if (n == 10) lds.u.s.zb[row0 + r][10] = f2bf_ru(tnext);
    }
    tcur = tnext;
  }
}

extern "C" void kernel_launch(void* const* d_in, const int* in_sizes, int n_in,
                              void* d_out, int out_size, void* d_ws, size_t ws_size,
                              hipStream_t stream) {
  (void)in_sizes; (void)n_in; (void)d_ws; (void)ws_size; (void)out_size;
  const float* z0       = (const float*)d_in[0];
  const float* activity = (const float*)d_in[1];
  const float* rest     = (const float*)d_in[2];
  const float* ts       = (const float*)d_in[3];
  const float* noise    = (const float*)d_in[4];
  const float* aW1 = (const float*)d_in[5];
  const float* ab1 = (const float*)d_in[6];
  const float* aW2 = (const float*)d_in[7];
  const float* ab2 = (const float*)d_in[8];
  const float* rW1 = (const float*)d_in[9];
  const float* rb1 = (const float*)d_in[10];
  const float* rW2 = (const float*)d_in[11];
  const float* rb2 = (const float*)d_in[12];
  const float* dW1 = (const float*)d_in[13];
  const float* db1 = (const float*)d_in[14];
  const float* dW2 = (const float*)d_in[15];
  const float* db2 = (const float*)d_in[16];
  const float* dW3 = (const float*)d_in[17];
  const float* db3 = (const float*)d_in[18];
  const float* gW1 = (const float*)d_in[19];
  const float* gb1 = (const float*)d_in[20];
  const float* gW2 = (const float*)d_in[21];
  const float* gb2 = (const float*)d_in[22];
  float* out = (float*)d_out;

  dim3 grid(B_TOT / MT), block(256);
  sde_kernel<<<grid, block, 0, stream>>>(
      z0, activity, rest, ts, noise,
      aW1, ab1, aW2, ab2, rW1, rb1, rW2, rb2,
      dW1, db1, dW2, db2, dW3, db3,
      gW1, gb1, gW2, gb2, out);
}

// Round 3
// 692.924 us; speedup vs baseline: 1.2329x; 1.2329x over previous
//
#include <hip/hip_runtime.h>
#include <cstdint>
#include <cstddef>

// LatentNeuralSDE: 100 sequential EM steps, B=32768, LAT=10.
// Persistent kernel, 512 blocks x 256 thr; wave owns 16 batch rows; no
// in-loop barriers (all LDS traffic is wave-private; per-wave DS ops are
// in-order). R3: hot-loop transcendentals via __builtin_amdgcn_* (one HW
// op each, no OCML calls); W2 frags 24-in-VGPR / 8-in-LDS; step-invariant
// z1/g1 frags in frag-linear LDS (re-read at step top, latency-hidable).

#define B_TOT 32768
#define NSTEP 100
#define MT    64

typedef __attribute__((ext_vector_type(8))) short sh8;
typedef __attribute__((ext_vector_type(4))) float f32x4;
typedef __attribute__((ext_vector_type(4))) unsigned int u32x4;

struct __align__(16) LdsSteady {
  short h[MT][136];    // hidden slab, storage col c -> feature (c&7)*16+(c>>3)
  short hg[MT][40];    // diffusion hidden, col c -> feature (c&1)*16+(c>>1)
  short zb[MT][40];    // [z0..z9, t, zeros...]; 80B rows (16B aligned)
};
struct __align__(16) LdsInit { float ar[MT][100]; };   // [a(64), r(32)]
struct __align__(16) Lds {
  union { LdsSteady s; LdsInit i; } u;   // 27648 B
  short w2l[8][64][8];                   // W2 frags t2=6..7, frag-linear
  short z1l[8][64][8];                   // L1 B-frags, frag-linear
  short g1l[2][64][8];                   // G1 B-frags, frag-linear
  float tsl[104];
};

static __device__ __forceinline__ short f2bf(float v) {  // RTNE (one-time paths)
  unsigned u = __builtin_bit_cast(unsigned, v);
  u += 0x7fffu + ((u >> 16) & 1u);
  return (short)(u >> 16);
}
static __device__ __forceinline__ short f2bf_ru(float v) {  // cheap round
  unsigned u = __builtin_bit_cast(unsigned, v) + 0x8000u;
  return (short)(u >> 16);
}
// pack two floats -> (bf16(hi)<<16)|bf16(lo) : 2 adds + 1 v_perm
static __device__ __forceinline__ unsigned pk2(float lo, float hi) {
  unsigned a = __builtin_bit_cast(unsigned, lo) + 0x8000u;
  unsigned b = __builtin_bit_cast(unsigned, hi) + 0x8000u;
  return __builtin_amdgcn_perm(b, a, 0x07060302u);
}
static __device__ __forceinline__ float tanh_fast(float x) {
  // 1 - 2/(1+2^(x*2/ln2)); v_exp + v_add + v_rcp + v_fma
  float e = __builtin_amdgcn_exp2f(x * 2.8853900817779268f);
  float r = __builtin_amdgcn_rcpf(e + 1.0f);
  return __builtin_fmaf(-2.0f, r, 1.0f);
}
static __device__ __forceinline__ float tanh_b(float x, float kb) {  // tanh(x+b)
  float e = __builtin_amdgcn_exp2f(__builtin_fmaf(x, 2.8853900817779268f, kb));
  float r = __builtin_amdgcn_rcpf(e + 1.0f);
  return __builtin_fmaf(-2.0f, r, 1.0f);
}
static __device__ __forceinline__ float softplus_fast(float x) {
  float e = __builtin_amdgcn_exp2f(x * 1.4426950408889634f);
  float l = __builtin_amdgcn_logf(e + 1.0f) * 0.6931471805599453f;
  return (x > 20.0f) ? x : l;
}

__global__ __launch_bounds__(256, 2)
void sde_kernel(const float* __restrict__ z0, const float* __restrict__ activity,
                const float* __restrict__ rest, const float* __restrict__ ts,
                const float* __restrict__ noise,
                const float* __restrict__ aW1, const float* __restrict__ ab1,
                const float* __restrict__ aW2, const float* __restrict__ ab2,
                const float* __restrict__ rW1, const float* __restrict__ rb1,
                const float* __restrict__ rW2, const float* __restrict__ rb2,
                const float* __restrict__ dW1, const float* __restrict__ db1,
                const float* __restrict__ dW2, const float* __restrict__ db2,
                const float* __restrict__ dW3, const float* __restrict__ db3,
                const float* __restrict__ gW1, const float* __restrict__ gb1,
                const float* __restrict__ gW2, const float* __restrict__ gb2,
                float* __restrict__ out)
{
  __shared__ Lds lds;
  const int tid  = threadIdx.x;
  const int lane = tid & 63;
  const int wave = tid >> 6;
  const int n    = lane & 15;
  const int quad = lane >> 4;
  const int slab = wave * 16;
  const int row0 = slab + quad * 4;
  const int mblk = blockIdx.x * MT;

  // ---------------- prologue: ts table ----------------
  if (tid < 101) lds.tsl[tid] = ts[tid];
  float tcur = ts[0];

  // ---------------- fragment builds ----------------
  // L1 B-frags -> z1l (all waves write identical data; benign)
  #pragma unroll
  for (int t = 0; t < 8; ++t) {
    short tmp[8];
    #pragma unroll
    for (int j = 0; j < 8; ++j) {
      int k = quad * 8 + j;
      float v = 0.0f;
      if (k < 10) v = dW1[k * 128 + t * 16 + n];
      else if (k == 10) v = dW1[106 * 128 + t * 16 + n];
      tmp[j] = f2bf(v);
    }
    *(sh8*)&lds.z1l[t][lane][0] =
        (sh8){tmp[0],tmp[1],tmp[2],tmp[3],tmp[4],tmp[5],tmp[6],tmp[7]};
  }
  // W2 frags vs permuted storage: elem j = W2[j*16+kt*4+quad][t2*16+n]
  sh8 w2r[6][4];
  #pragma unroll
  for (int t2 = 0; t2 < 8; ++t2) {
    #pragma unroll
    for (int kt = 0; kt < 4; ++kt) {
      short tmp[8];
      #pragma unroll
      for (int j = 0; j < 8; ++j)
        tmp[j] = f2bf(dW2[(j * 16 + kt * 4 + quad) * 128 + t2 * 16 + n]);
      sh8 f = (sh8){tmp[0],tmp[1],tmp[2],tmp[3],tmp[4],tmp[5],tmp[6],tmp[7]};
      if (t2 < 6) w2r[t2][kt] = f;
      else *(sh8*)&lds.w2l[(t2 - 6) * 4 + kt][lane][0] = f;
    }
  }
  // W3 frags (same row permutation)
  sh8 w3f[4];
  #pragma unroll
  for (int kt = 0; kt < 4; ++kt) {
    short tmp[8];
    #pragma unroll
    for (int j = 0; j < 8; ++j) {
      int rr = j * 16 + kt * 4 + quad;
      tmp[j] = f2bf((n < 10) ? dW3[rr * 10 + n] : 0.0f);
    }
    w3f[kt] = (sh8){tmp[0],tmp[1],tmp[2],tmp[3],tmp[4],tmp[5],tmp[6],tmp[7]};
  }
  // G1 frags -> g1l
  #pragma unroll
  for (int t = 0; t < 2; ++t) {
    short tmp[8];
    #pragma unroll
    for (int j = 0; j < 8; ++j) {
      int k = quad * 8 + j;
      float v = 0.0f;
      if (k < 10) v = gW1[k * 32 + t * 16 + n];
      else if (k == 10) v = gW1[10 * 32 + t * 16 + n];
      tmp[j] = f2bf(v);
    }
    *(sh8*)&lds.g1l[t][lane][0] =
        (sh8){tmp[0],tmp[1],tmp[2],tmp[3],tmp[4],tmp[5],tmp[6],tmp[7]};
  }
  // G2 frag vs hg permutation: k -> feature (k&1)*16 + (k>>1)
  sh8 g2f;
  {
    short tmp[8];
    #pragma unroll
    for (int j = 0; j < 8; ++j) {
      int k = quad * 8 + j;
      int f = (k & 1) * 16 + (k >> 1);
      tmp[j] = f2bf((n < 10) ? gW2[f * 10 + n] : 0.0f);
    }
    g2f = (sh8){tmp[0],tmp[1],tmp[2],tmp[3],tmp[4],tmp[5],tmp[6],tmp[7]};
  }
  // bias folds
  float kb2[8];
  #pragma unroll
  for (int t = 0; t < 8; ++t) kb2[t] = db2[t * 16 + n] * 2.8853900817779268f;
  float gb1a = gb1[n], gb1b_ = gb1[16 + n];
  float db3r = (n < 10) ? db3[n] : 0.0f;
  float gb2r = (n < 10) ? gb2[n] : 0.0f;
  const f32x4 cg0 = {gb1a, gb1a, gb1a, gb1a};
  const f32x4 cg1 = {gb1b_, gb1b_, gb1b_, gb1b_};
  const f32x4 cd3 = {db3r, db3r, db3r, db3r};
  const f32x4 cg2 = {gb2r, gb2r, gb2r, gb2r};
  const f32x4 zc  = {0.0f, 0.0f, 0.0f, 0.0f};

  // ---------------- encoders -> ar ----------------
  {
    const int e = tid >> 2, p = tid & 3;
    const int eg = mblk + e;
    float act[6], rst[3];
    #pragma unroll
    for (int i = 0; i < 6; ++i) act[i] = activity[eg * 6 + i];
    #pragma unroll
    for (int i = 0; i < 3; ++i) rst[i] = rest[eg * 3 + i];
    float ha[32];
    for (int j = 0; j < 32; ++j) {
      float s = ab1[j];
      #pragma unroll
      for (int i = 0; i < 6; ++i) s = __builtin_fmaf(act[i], aW1[i * 32 + j], s);
      ha[j] = fmaxf(s, 0.0f);
    }
    float hr[16];
    for (int j = 0; j < 16; ++j) {
      float s = rb1[j];
      #pragma unroll
      for (int i = 0; i < 3; ++i) s = __builtin_fmaf(rst[i], rW1[i * 16 + j], s);
      hr[j] = fmaxf(s, 0.0f);
    }
    for (int oo = 0; oo < 24; ++oo) {
      int o = p * 24 + oo;
      float v;
      if (o < 64) {
        v = ab2[o];
        for (int j = 0; j < 32; ++j) v = __builtin_fmaf(ha[j], aW2[j * 64 + o], v);
      } else {
        int ro = o - 64;
        v = rb2[ro];
        for (int j = 0; j < 16; ++j) v = __builtin_fmaf(hr[j], rW2[j * 32 + ro], v);
      }
      lds.u.i.ar[e][o] = v;
    }
  }
  __syncthreads();

  // ---------------- c1 context fold (C operand for L1) ----------------
  f32x4 c1v[8];
  #pragma unroll
  for (int t = 0; t < 8; ++t) {
    float b = db1[t * 16 + n];
    c1v[t] = (f32x4){b, b, b, b};
  }
  for (int k = 0; k < 96; ++k) {
    float w[8];
    #pragma unroll
    for (int t = 0; t < 8; ++t) w[t] = dW1[(10 + k) * 128 + t * 16 + n];
    #pragma unroll
    for (int r = 0; r < 4; ++r) {
      float av = lds.u.i.ar[row0 + r][k];
      #pragma unroll
      for (int t = 0; t < 8; ++t) c1v[t][r] = __builtin_fmaf(av, w[t], c1v[t][r]);
    }
  }
  __syncthreads();   // ar dead; steady region live. Last barrier.

  // ---------------- zb init (wave-private), z0 load, out[0] ----------------
  {
    short* zp = &lds.u.s.zb[slab][0];
    for (int i = lane; i < 16 * 40; i += 64) zp[i] = 0;
  }
  float zreg[4];
  {
    float* op0 = out + (size_t)(mblk + row0) * 10 + n;
    #pragma unroll
    for (int r = 0; r < 4; ++r) {
      float v = (n < 10) ? z0[(size_t)(mblk + row0 + r) * 10 + n] : 0.0f;
      zreg[r] = v;
      if (n < 10) op0[r * 10] = v;
    }
    #pragma unroll
    for (int r = 0; r < 4; ++r) {
      if (n < 10)       lds.u.s.zb[row0 + r][n]  = f2bf_ru(zreg[r]);
      else if (n == 10) lds.u.s.zb[row0 + r][10] = f2bf_ru(tcur);
    }
  }

  // precomputed addresses
  const short* zb_rd = &lds.u.s.zb[slab + n][quad * 8];
  const short* h_rd  = &lds.u.s.h[slab + n][quad * 8];
  const short* hg_rd = &lds.u.s.hg[slab + n][quad * 8];
  const float* np = noise + (size_t)(mblk + row0) * 10 + n;
  float*       op = out + (size_t)B_TOT * 10 + (size_t)(mblk + row0) * 10 + n;

  #pragma unroll 1
  for (int s = 0; s < NSTEP; ++s) {
    float tnext = lds.tsl[s + 1];
    float dtv   = tnext - tcur;
    float sdt   = __builtin_amdgcn_sqrtf(dtv);

    // noise prefetch (used ~whole step later)
    float eps[4] = {0.0f, 0.0f, 0.0f, 0.0f};
    if (n < 10) { eps[0] = np[0]; eps[1] = np[10]; eps[2] = np[20]; eps[3] = np[30]; }
    np += (size_t)B_TOT * 10;

    // step-invariant frag reloads (no upstream dependency -> hidden)
    sh8 z1v[8];
    #pragma unroll
    for (int t = 0; t < 8; ++t) z1v[t] = *(const sh8*)&lds.z1l[t][lane][0];
    sh8 g1v0 = *(const sh8*)&lds.g1l[0][lane][0];
    sh8 g1v1 = *(const sh8*)&lds.g1l[1][lane][0];

    sh8 zA = *(const sh8*)zb_rd;

    // ---- diffusion hidden: hg = softplus(z,t @ G1 + gb1) ----
    {
      f32x4 g0 = __builtin_amdgcn_mfma_f32_16x16x32_bf16(zA, g1v0, cg0, 0, 0, 0);
      f32x4 g1 = __builtin_amdgcn_mfma_f32_16x16x32_bf16(zA, g1v1, cg1, 0, 0, 0);
      #pragma unroll
      for (int r = 0; r < 4; ++r)
        *(unsigned*)&lds.u.s.hg[row0 + r][n * 2] =
            pk2(softplus_fast(g0[r]), softplus_fast(g1[r]));
    }

    // ---- drift L1: h1 = tanh(z,t @ W1z + c1) ----
    {
      f32x4 a1[8];
      #pragma unroll
      for (int t = 0; t < 8; ++t)
        a1[t] = __builtin_amdgcn_mfma_f32_16x16x32_bf16(zA, z1v[t], c1v[t], 0, 0, 0);
      #pragma unroll
      for (int r = 0; r < 4; ++r) {
        u32x4 w;
        w.x = pk2(tanh_fast(a1[0][r]), tanh_fast(a1[1][r]));
        w.y = pk2(tanh_fast(a1[2][r]), tanh_fast(a1[3][r]));
        w.z = pk2(tanh_fast(a1[4][r]), tanh_fast(a1[5][r]));
        w.w = pk2(tanh_fast(a1[6][r]), tanh_fast(a1[7][r]));
        *(u32x4*)&lds.u.s.h[row0 + r][n * 8] = w;
      }
    }

    // ---- drift L2: h2 = tanh(h1 @ W2 + db2) ----
    {
      sh8 a2k[4];
      #pragma unroll
      for (int kt = 0; kt < 4; ++kt)
        a2k[kt] = *(const sh8*)(h_rd + kt * 32);
      f32x4 a2[8];
      #pragma unroll
      for (int t2 = 0; t2 < 8; ++t2) {
        f32x4 acc = zc;
        #pragma unroll
        for (int kt = 0; kt < 4; ++kt) {
          sh8 b = (t2 < 6) ? w2r[t2][kt]
                           : *(const sh8*)&lds.w2l[(t2 - 6) * 4 + kt][lane][0];
          acc = __builtin_amdgcn_mfma_f32_16x16x32_bf16(a2k[kt], b, acc, 0, 0, 0);
        }
        a2[t2] = acc;
      }
      #pragma unroll
      for (int r = 0; r < 4; ++r) {
        u32x4 w;
        w.x = pk2(tanh_b(a2[0][r], kb2[0]), tanh_b(a2[1][r], kb2[1]));
        w.y = pk2(tanh_b(a2[2][r], kb2[2]), tanh_b(a2[3][r], kb2[3]));
        w.z = pk2(tanh_b(a2[4][r], kb2[4]), tanh_b(a2[5][r], kb2[5]));
        w.w = pk2(tanh_b(a2[6][r], kb2[6]), tanh_b(a2[7][r], kb2[7]));
        *(u32x4*)&lds.u.s.h[row0 + r][n * 8] = w;
      }
    }

    // ---- drift L3 + diffusion out ----
    f32x4 accd = cd3;
    {
      sh8 a3k[4];
      #pragma unroll
      for (int kt = 0; kt < 4; ++kt)
        a3k[kt] = *(const sh8*)(h_rd + kt * 32);
      #pragma unroll
      for (int kt = 0; kt < 4; ++kt)
        accd = __builtin_amdgcn_mfma_f32_16x16x32_bf16(a3k[kt], w3f[kt], accd, 0, 0, 0);
    }
    f32x4 accf;
    {
      sh8 ag = *(const sh8*)hg_rd;
      accf = __builtin_amdgcn_mfma_f32_16x16x32_bf16(ag, g2f, cg2, 0, 0, 0);
    }

    // ---- EM update, out store, zb refresh ----
    #pragma unroll
    for (int r = 0; r < 4; ++r) {
      float d = __builtin_fmaf(accd[r], dtv, zreg[r]);
      zreg[r] = __builtin_fmaf(accf[r] * sdt, eps[r], d);
    }
    if (n < 10) {
      op[0] = zreg[0]; op[10] = zreg[1]; op[20] = zreg[2]; op[30] = zreg[3];
    }
    op += (size_t)B_TOT * 10;
    #pragma unroll
    for (int r = 0; r < 4; ++r) {
      if (n < 10)       lds.u.s.zb[row0 + r][n]  = f2bf_ru(zreg[r]);
      else if (n == 10) lds.u.s.zb[row0 + r][10] = f2bf_ru(tnext);
    }
    tcur = tnext;
  }
}

extern "C" void kernel_launch(void* const* d_in, const int* in_sizes, int n_in,
                              void* d_out, int out_size, void* d_ws, size_t ws_size,
                              hipStream_t stream) {
  (void)in_sizes; (void)n_in; (void)d_ws; (void)ws_size; (void)out_size;
  const float* z0       = (const float*)d_in[0];
  const float* activity = (const float*)d_in[1];
  const float* rest     = (const float*)d_in[2];
  const float* ts       = (const float*)d_in[3];
  const float* noise    = (const float*)d_in[4];
  const float* aW1 = (const float*)d_in[5];
  const float* ab1 = (const float*)d_in[6];
  const float* aW2 = (const float*)d_in[7];
  const float* ab2 = (const float*)d_in[8];
  const float* rW1 = (const float*)d_in[9];
  const float* rb1 = (const float*)d_in[10];
  const float* rW2 = (const float*)d_in[11];
  const float* rb2 = (const float*)d_in[12];
  const float* dW1 = (const float*)d_in[13];
  const float* db1 = (const float*)d_in[14];
  const float* dW2 = (const float*)d_in[15];
  const float* db2 = (const float*)d_in[16];
  const float* dW3 = (const float*)d_in[17];
  const float* db3 = (const float*)d_in[18];
  const float* gW1 = (const float*)d_in[19];
  const float* gb1 = (const float*)d_in[20];
  const float* gW2 = (const float*)d_in[21];
  const float* gb2 = (const float*)d_in[22];
  float* out = (float*)d_out;

  dim3 grid(B_TOT / MT), block(256);
  sde_kernel<<<grid, block, 0, stream>>>(
      z0, activity, rest, ts, noise,
      aW1, ab1, aW2, ab2, rW1, rb1, rW2, rb2,
      dW1, db1, dW2, db2, dW3, db3,
      gW1, gb1, gW2, gb2, out);
}